// Round 13
// baseline (100.603 us; speedup 1.0000x reference)
//
#include <hip/hip_runtime.h>

#define BB 8
#define CC 64
#define UU 3
#define NN 512
#define POS (UU * NN)               // 1536
#define QKV_ELEMS (BB * CC * POS)   // 786432 floats per tensor
// 0.125 (= C^-0.5) * log2(e), folded into q so softmax uses raw exp2
#define SCALE2 0.1803368801111793f

typedef float f2 __attribute__((ext_vector_type(2)));

// ---------------- Kernel 1: projection (byte-identical to round 12) --------
__global__ __launch_bounds__(256) void proj_kernel(
    const float* __restrict__ x,
    const float* __restrict__ Wq,
    const float* __restrict__ Wk,
    const float* __restrict__ Wv,
    float* __restrict__ ws)
{
    const int blk  = blockIdx.x;         // 0..767
    const int b    = blk & 7;            // XCD-locality
    const int rest = blk >> 3;           // 0..95
    const int d0   = (rest / 6) * 4;     // 16 d-quads
    const int chunk= rest % 6;
    const int p    = chunk * 256 + threadIdx.x;   // 0..1535

    const float* wq = Wq + (size_t)d0 * CC;   // block-uniform rows
    const float* wk = Wk + (size_t)d0 * CC;
    const float* wv = Wv + (size_t)d0 * CC;
    const float* xb = x + (size_t)b * CC * POS + p;

    float qa[4] = {0.f, 0.f, 0.f, 0.f};
    float ka[4] = {0.f, 0.f, 0.f, 0.f};
    float va[4] = {0.f, 0.f, 0.f, 0.f};

    #pragma unroll 4
    for (int c = 0; c < CC; ++c) {
        float xv = xb[c * POS];
        #pragma unroll
        for (int r = 0; r < 4; ++r) {
            qa[r] = fmaf(xv, wq[r * CC + c], qa[r]);   // uniform -> s_load
            ka[r] = fmaf(xv, wk[r * CC + c], ka[r]);
            va[r] = fmaf(xv, wv[r * CC + c], va[r]);
        }
    }

    float* qs = ws;
    float* ks = ws + QKV_ELEMS;
    float* vs = ws + 2 * QKV_ELEMS;
    #pragma unroll
    for (int r = 0; r < 4; ++r) {
        size_t base = (size_t)(b * CC + d0 + r) * POS + p;
        qs[base] = qa[r] * SCALE2;
        ks[base] = ka[r];
        vs[base] = va[r];
    }
}

// ---------------- Kernel 2: attention, R=8 rows/thread, 4-way j-split ------
// grid = 512 (one bd per block, 2 blocks/CU). slot = tid>>2 (64 slots),
// h = tid&3 (128-j quarter). Thread owns rows {slot + m*64, m=0..7}.
// Each 6x ds_read_b128 (96 B K/V) serves 8 rows x 4 j = 32 pairs -> 3 B/pair,
// putting the CU-shared LDS return bus (~5 us floor) safely under the
// pk-compute floor (~13 us). 8-deep m-loop = dense independent ILP.
__global__ __launch_bounds__(256) void attn_kernel(
    const float* __restrict__ x,
    const float* __restrict__ ws,
    float* __restrict__ out)
{
    const int bd  = blockIdx.x;    // 0..511
    const int tid = threadIdx.x;

    __shared__ __align__(16) float ks[UU][NN];
    __shared__ __align__(16) float vs[UU][NN];
    __shared__ float4 part[NN];    // (a0, a1, a2, l) per row

    const float* qsg = ws + (size_t)bd * POS;
    const float* ksg = ws + QKV_ELEMS     + (size_t)bd * POS;
    const float* vsg = ws + 2 * QKV_ELEMS + (size_t)bd * POS;

    // stage K and V (6 KB each, contiguous) as float4
    {
        const float4* kg4 = (const float4*)ksg;
        const float4* vg4 = (const float4*)vsg;
        float4* ks4 = (float4*)&ks[0][0];
        float4* vs4 = (float4*)&vs[0][0];
        #pragma unroll
        for (int it = 0; it < 3; ++it) {
            int idx = tid + it * 256;        // 0..767
            if (idx < 384) ks4[idx] = kg4[idx];
            else           vs4[idx - 384] = vg4[idx - 384];
        }
    }
    __syncthreads();

    const int h    = tid & 3;      // j-quarter
    const int slot = tid >> 2;     // 0..63

    f2 Q0[8], Q1[8], Q2[8];
    #pragma unroll
    for (int m = 0; m < 8; ++m) {
        int i = slot + m * 64;
        float a = qsg[i], b = qsg[NN + i], c = qsg[2 * NN + i];
        Q0[m] = (f2){a, a};
        Q1[m] = (f2){b, b};
        Q2[m] = (f2){c, c};
    }

    f2 L[8], A0[8], A1[8], A2[8];
    #pragma unroll
    for (int m = 0; m < 8; ++m) {
        L[m] = (f2){0.f, 0.f};  A0[m] = (f2){0.f, 0.f};
        A1[m] = (f2){0.f, 0.f}; A2[m] = (f2){0.f, 0.f};
    }

    const float4* k0p = (const float4*)&ks[0][0] + h * 32;
    const float4* k1p = (const float4*)&ks[1][0] + h * 32;
    const float4* k2p = (const float4*)&ks[2][0] + h * 32;
    const float4* v0p = (const float4*)&vs[0][0] + h * 32;
    const float4* v1p = (const float4*)&vs[1][0] + h * 32;
    const float4* v2p = (const float4*)&vs[2][0] + h * 32;
    const int t0 = 2 * h;          // bank-stagger offset

    for (int tt = 0; tt < 32; ++tt) {
        const int t = (tt + t0) & 31;
        float4 k0 = k0p[t];
        float4 k1 = k1p[t];
        float4 k2 = k2p[t];
        float4 v0 = v0p[t];
        float4 v1 = v1p[t];
        float4 v2 = v2p[t];

        f2 k0a = (f2){k0.x, k0.y}, k0b = (f2){k0.z, k0.w};
        f2 k1a = (f2){k1.x, k1.y}, k1b = (f2){k1.z, k1.w};
        f2 k2a = (f2){k2.x, k2.y}, k2b = (f2){k2.z, k2.w};
        f2 v0a = (f2){v0.x, v0.y}, v0b = (f2){v0.z, v0.w};
        f2 v1a = (f2){v1.x, v1.y}, v1b = (f2){v1.z, v1.w};
        f2 v2a = (f2){v2.x, v2.y}, v2b = (f2){v2.z, v2.w};

        #pragma unroll
        for (int m = 0; m < 8; ++m) {
            f2 sa = __builtin_elementwise_fma(Q0[m], k0a,
                     __builtin_elementwise_fma(Q1[m], k1a, Q2[m] * k2a));
            f2 sb = __builtin_elementwise_fma(Q0[m], k0b,
                     __builtin_elementwise_fma(Q1[m], k1b, Q2[m] * k2b));

            f2 pa = (f2){__builtin_amdgcn_exp2f(sa.x), __builtin_amdgcn_exp2f(sa.y)};
            f2 pb = (f2){__builtin_amdgcn_exp2f(sb.x), __builtin_amdgcn_exp2f(sb.y)};

            L[m]  = L[m] + pa + pb;
            A0[m] = __builtin_elementwise_fma(pa, v0a,
                      __builtin_elementwise_fma(pb, v0b, A0[m]));
            A1[m] = __builtin_elementwise_fma(pa, v1a,
                      __builtin_elementwise_fma(pb, v1b, A1[m]));
            A2[m] = __builtin_elementwise_fma(pa, v2a,
                      __builtin_elementwise_fma(pb, v2b, A2[m]));
        }
    }

    // collapse packed halves, merge the 4 j-quarters (4-lane butterfly)
    #pragma unroll
    for (int m = 0; m < 8; ++m) {
        float l  = L[m].x  + L[m].y;
        float a0 = A0[m].x + A0[m].y;
        float a1 = A1[m].x + A1[m].y;
        float a2 = A2[m].x + A2[m].y;

        l  += __shfl_xor(l,  1);  l  += __shfl_xor(l,  2);
        a0 += __shfl_xor(a0, 1);  a0 += __shfl_xor(a0, 2);
        a1 += __shfl_xor(a1, 1);  a1 += __shfl_xor(a1, 2);
        a2 += __shfl_xor(a2, 1);  a2 += __shfl_xor(a2, 2);

        if (h == 0) part[slot + m * 64] = make_float4(a0, a1, a2, l);
    }
    __syncthreads();

    // coalesced epilogue: thread t finalizes rows t and t+256
    const float* xd = x   + (size_t)bd * POS;
    float*       od = out + (size_t)bd * POS;
    #pragma unroll
    for (int w = 0; w < 2; ++w) {
        int i = tid + w * 256;
        float4 P = part[i];
        float inv = 1.0f / P.w;
        od[i]          = xd[i]          + P.x * inv;
        od[NN + i]     = xd[NN + i]     + P.y * inv;
        od[2 * NN + i] = xd[2 * NN + i] + P.z * inv;
    }
}

// ---------------- Fallback: fused kernel (if ws too small) -----------------
__global__ __launch_bounds__(256) void vn_attn_fused(
    const float* __restrict__ x,
    const float* __restrict__ Wq,
    const float* __restrict__ Wk,
    const float* __restrict__ Wv,
    float* __restrict__ out)
{
    const int bd  = blockIdx.x;
    const int b   = bd / CC;
    const int d   = bd % CC;
    const int tid = threadIdx.x;

    __shared__ float wq[CC], wk[CC], wv[CC];
    __shared__ float qs[UU][NN];
    __shared__ float ks[UU][NN];
    __shared__ float vs[UU][NN];

    if (tid < CC) {
        wq[tid] = Wq[d * CC + tid];
        wk[tid] = Wk[d * CC + tid];
        wv[tid] = Wv[d * CC + tid];
    }
    __syncthreads();

    const float* xb = x + (size_t)b * CC * POS;
    for (int p = tid; p < POS; p += 256) {
        float qa = 0.f, ka = 0.f, va = 0.f;
        #pragma unroll 8
        for (int c = 0; c < CC; ++c) {
            float xv = xb[c * POS + p];
            qa = fmaf(xv, wq[c], qa);
            ka = fmaf(xv, wk[c], ka);
            va = fmaf(xv, wv[c], va);
        }
        int u = p >> 9, n = p & (NN - 1);
        qs[u][n] = qa * SCALE2;
        ks[u][n] = ka;
        vs[u][n] = va;
    }
    __syncthreads();

    for (int i = tid; i < NN; i += 256) {
        float q0 = qs[0][i], q1 = qs[1][i], q2 = qs[2][i];
        float l = 0.f, a0 = 0.f, a1 = 0.f, a2 = 0.f;
        for (int j = 0; j < NN; j += 4) {
            float4 k0 = *(const float4*)&ks[0][j];
            float4 k1 = *(const float4*)&ks[1][j];
            float4 k2 = *(const float4*)&ks[2][j];
            float4 v0 = *(const float4*)&vs[0][j];
            float4 v1 = *(const float4*)&vs[1][j];
            float4 v2 = *(const float4*)&vs[2][j];
            float s0 = fmaf(q0, k0.x, fmaf(q1, k1.x, q2 * k2.x));
            float s1 = fmaf(q0, k0.y, fmaf(q1, k1.y, q2 * k2.y));
            float s2 = fmaf(q0, k0.z, fmaf(q1, k1.z, q2 * k2.z));
            float s3 = fmaf(q0, k0.w, fmaf(q1, k1.w, q2 * k2.w));
            float p0 = __builtin_amdgcn_exp2f(s0);
            float p1 = __builtin_amdgcn_exp2f(s1);
            float p2 = __builtin_amdgcn_exp2f(s2);
            float p3 = __builtin_amdgcn_exp2f(s3);
            l += p0 + p1 + p2 + p3;
            a0 = fmaf(p0, v0.x, fmaf(p1, v0.y, fmaf(p2, v0.z, fmaf(p3, v0.w, a0))));
            a1 = fmaf(p0, v1.x, fmaf(p1, v1.y, fmaf(p2, v1.z, fmaf(p3, v1.w, a1))));
            a2 = fmaf(p0, v2.x, fmaf(p1, v2.y, fmaf(p2, v2.z, fmaf(p3, v2.w, a2))));
        }
        float inv = 1.0f / l;
        size_t obase = ((size_t)(b * CC + d) * UU) * NN + i;
        const float* xd = xb + (size_t)d * POS;
        out[obase]          = xd[i]          + a0 * inv;
        out[obase + NN]     = xd[NN + i]     + a1 * inv;
        out[obase + 2 * NN] = xd[2 * NN + i] + a2 * inv;
    }
}

extern "C" void kernel_launch(void* const* d_in, const int* in_sizes, int n_in,
                              void* d_out, int out_size, void* d_ws, size_t ws_size,
                              hipStream_t stream) {
    const float* x  = (const float*)d_in[0];
    const float* Wq = (const float*)d_in[1];
    const float* Wk = (const float*)d_in[2];
    const float* Wv = (const float*)d_in[3];
    float* out = (float*)d_out;

    if (ws_size >= (size_t)3 * QKV_ELEMS * sizeof(float)) {
        float* ws = (float*)d_ws;
        proj_kernel<<<dim3(8 * 16 * 6), dim3(256), 0, stream>>>(x, Wq, Wk, Wv, ws);
        attn_kernel<<<dim3(BB * CC), dim3(256), 0, stream>>>(x, ws, out);
    } else {
        vn_attn_fused<<<dim3(BB * CC), dim3(256), 0, stream>>>(x, Wq, Wk, Wv, out);
    }
}

// Round 14
// 97.817 us; speedup vs baseline: 1.0285x; 1.0285x over previous
//
#include <hip/hip_runtime.h>

#define BB 8
#define CC 64
#define UU 3
#define NN 512
#define POS (UU * NN)               // 1536
// 0.125 (= C^-0.5) * log2(e), folded into q so softmax uses raw exp2
#define SCALE2 0.1803368801111793f

typedef float f2 __attribute__((ext_vector_type(2)));

// ---------------- Single fused kernel: proj + attention + residual ---------
// grid = 512 (one (b,d) per block), 256 threads, 2 blocks/CU.
// Phase 1: W[d] rows -> LDS (768 B, broadcast reads).
// Phase 2: proj. Thread owns n-pair (2*tid, 2*tid+1) for u=0,1,2: per c-iter
//   3 f2 global loads (8 B coalesced) + 9 pk-FMA. x[b] = 393 KB, L2-resident
//   across the 64 blocks sharing it. q scaled by SCALE2 on LDS write.
// Phase 3: attention, r13 structure: h = tid&3 j-quarter, slot = tid>>2,
//   R=8 rows/thread, packed-f2 math, bank-staggered b128 K/V reads,
//   4-lane butterfly merge, LDS part[] staging, coalesced epilogue.
__global__ __launch_bounds__(256) void vn_fused_kernel(
    const float* __restrict__ x,
    const float* __restrict__ Wq,
    const float* __restrict__ Wk,
    const float* __restrict__ Wv,
    float* __restrict__ out)
{
    const int bd  = blockIdx.x;    // 0..511
    const int b   = bd >> 6;
    const int d   = bd & 63;
    const int tid = threadIdx.x;

    __shared__ float w[3][CC];     // W[d] rows: q, k, v
    __shared__ __align__(16) float qs[UU][NN];
    __shared__ __align__(16) float ks[UU][NN];
    __shared__ __align__(16) float vs[UU][NN];
    __shared__ float4 part[NN];    // (a0, a1, a2, l) per row

    if (tid < 192) {
        int r = tid >> 6, c = tid & 63;
        const float* W = (r == 0) ? Wq : (r == 1) ? Wk : Wv;
        w[r][c] = W[d * CC + c];
    }
    __syncthreads();

    // ---- Phase 2: projection ----
    {
        const float* xb = x + (size_t)b * CC * POS;
        const int p0 = tid * 2;            // n-pair base, u-stride 512

        f2 qa0 = {0.f,0.f}, qa1 = {0.f,0.f}, qa2 = {0.f,0.f};
        f2 ka0 = {0.f,0.f}, ka1 = {0.f,0.f}, ka2 = {0.f,0.f};
        f2 va0 = {0.f,0.f}, va1 = {0.f,0.f}, va2 = {0.f,0.f};

        #pragma unroll 4
        for (int c = 0; c < CC; ++c) {
            const float* xc = xb + c * POS + p0;
            f2 x0 = *(const f2*)(xc);
            f2 x1 = *(const f2*)(xc + NN);
            f2 x2 = *(const f2*)(xc + 2 * NN);
            float wqc = w[0][c], wkc = w[1][c], wvc = w[2][c];
            f2 wq2 = {wqc, wqc}, wk2 = {wkc, wkc}, wv2 = {wvc, wvc};
            qa0 = __builtin_elementwise_fma(x0, wq2, qa0);
            qa1 = __builtin_elementwise_fma(x1, wq2, qa1);
            qa2 = __builtin_elementwise_fma(x2, wq2, qa2);
            ka0 = __builtin_elementwise_fma(x0, wk2, ka0);
            ka1 = __builtin_elementwise_fma(x1, wk2, ka1);
            ka2 = __builtin_elementwise_fma(x2, wk2, ka2);
            va0 = __builtin_elementwise_fma(x0, wv2, va0);
            va1 = __builtin_elementwise_fma(x1, wv2, va1);
            va2 = __builtin_elementwise_fma(x2, wv2, va2);
        }

        f2 sc = {SCALE2, SCALE2};
        *(f2*)&qs[0][p0] = qa0 * sc;
        *(f2*)&qs[1][p0] = qa1 * sc;
        *(f2*)&qs[2][p0] = qa2 * sc;
        *(f2*)&ks[0][p0] = ka0;
        *(f2*)&ks[1][p0] = ka1;
        *(f2*)&ks[2][p0] = ka2;
        *(f2*)&vs[0][p0] = va0;
        *(f2*)&vs[1][p0] = va1;
        *(f2*)&vs[2][p0] = va2;
    }
    __syncthreads();

    // ---- Phase 3: attention ----
    const int h    = tid & 3;      // j-quarter
    const int slot = tid >> 2;     // 0..63

    f2 Q0[8], Q1[8], Q2[8];
    #pragma unroll
    for (int m = 0; m < 8; ++m) {
        int i = slot + m * 64;
        float a = qs[0][i], bq = qs[1][i], c = qs[2][i];
        Q0[m] = (f2){a, a};
        Q1[m] = (f2){bq, bq};
        Q2[m] = (f2){c, c};
    }

    f2 L[8], A0[8], A1[8], A2[8];
    #pragma unroll
    for (int m = 0; m < 8; ++m) {
        L[m] = (f2){0.f, 0.f};  A0[m] = (f2){0.f, 0.f};
        A1[m] = (f2){0.f, 0.f}; A2[m] = (f2){0.f, 0.f};
    }

    const float4* k0p = (const float4*)&ks[0][0] + h * 32;
    const float4* k1p = (const float4*)&ks[1][0] + h * 32;
    const float4* k2p = (const float4*)&ks[2][0] + h * 32;
    const float4* v0p = (const float4*)&vs[0][0] + h * 32;
    const float4* v1p = (const float4*)&vs[1][0] + h * 32;
    const float4* v2p = (const float4*)&vs[2][0] + h * 32;
    const int t0 = 2 * h;          // bank-stagger offset

    for (int tt = 0; tt < 32; ++tt) {
        const int t = (tt + t0) & 31;
        float4 k0 = k0p[t];
        float4 k1 = k1p[t];
        float4 k2 = k2p[t];
        float4 v0 = v0p[t];
        float4 v1 = v1p[t];
        float4 v2 = v2p[t];

        f2 k0a = (f2){k0.x, k0.y}, k0b = (f2){k0.z, k0.w};
        f2 k1a = (f2){k1.x, k1.y}, k1b = (f2){k1.z, k1.w};
        f2 k2a = (f2){k2.x, k2.y}, k2b = (f2){k2.z, k2.w};
        f2 v0a = (f2){v0.x, v0.y}, v0b = (f2){v0.z, v0.w};
        f2 v1a = (f2){v1.x, v1.y}, v1b = (f2){v1.z, v1.w};
        f2 v2a = (f2){v2.x, v2.y}, v2b = (f2){v2.z, v2.w};

        #pragma unroll
        for (int m = 0; m < 8; ++m) {
            f2 sa = __builtin_elementwise_fma(Q0[m], k0a,
                     __builtin_elementwise_fma(Q1[m], k1a, Q2[m] * k2a));
            f2 sb = __builtin_elementwise_fma(Q0[m], k0b,
                     __builtin_elementwise_fma(Q1[m], k1b, Q2[m] * k2b));

            f2 pa = (f2){__builtin_amdgcn_exp2f(sa.x), __builtin_amdgcn_exp2f(sa.y)};
            f2 pb = (f2){__builtin_amdgcn_exp2f(sb.x), __builtin_amdgcn_exp2f(sb.y)};

            L[m]  = L[m] + pa + pb;
            A0[m] = __builtin_elementwise_fma(pa, v0a,
                      __builtin_elementwise_fma(pb, v0b, A0[m]));
            A1[m] = __builtin_elementwise_fma(pa, v1a,
                      __builtin_elementwise_fma(pb, v1b, A1[m]));
            A2[m] = __builtin_elementwise_fma(pa, v2a,
                      __builtin_elementwise_fma(pb, v2b, A2[m]));
        }
    }

    // merge the 4 j-quarters (4-lane butterfly) and stage per-row results
    #pragma unroll
    for (int m = 0; m < 8; ++m) {
        float l  = L[m].x  + L[m].y;
        float a0 = A0[m].x + A0[m].y;
        float a1 = A1[m].x + A1[m].y;
        float a2 = A2[m].x + A2[m].y;

        l  += __shfl_xor(l,  1);  l  += __shfl_xor(l,  2);
        a0 += __shfl_xor(a0, 1);  a0 += __shfl_xor(a0, 2);
        a1 += __shfl_xor(a1, 1);  a1 += __shfl_xor(a1, 2);
        a2 += __shfl_xor(a2, 1);  a2 += __shfl_xor(a2, 2);

        if (h == 0) part[slot + m * 64] = make_float4(a0, a1, a2, l);
    }
    __syncthreads();

    // coalesced epilogue: thread t finalizes rows t and t+256
    const float* xd = x   + (size_t)bd * POS;
    float*       od = out + (size_t)bd * POS;
    #pragma unroll
    for (int wi = 0; wi < 2; ++wi) {
        int i = tid + wi * 256;
        float4 P = part[i];
        float inv = 1.0f / P.w;
        od[i]          = xd[i]          + P.x * inv;
        od[NN + i]     = xd[NN + i]     + P.y * inv;
        od[2 * NN + i] = xd[2 * NN + i] + P.z * inv;
    }
}

extern "C" void kernel_launch(void* const* d_in, const int* in_sizes, int n_in,
                              void* d_out, int out_size, void* d_ws, size_t ws_size,
                              hipStream_t stream) {
    const float* x  = (const float*)d_in[0];
    const float* Wq = (const float*)d_in[1];
    const float* Wk = (const float*)d_in[2];
    const float* Wv = (const float*)d_in[3];
    float* out = (float*)d_out;

    vn_fused_kernel<<<dim3(BB * CC), dim3(256), 0, stream>>>(x, Wq, Wk, Wv, out);
}